// Round 7
// baseline (517.945 us; speedup 1.0000x reference)
//
#include <hip/hip_runtime.h>
#include <math.h>

#define NLEV 16
#define TBL (1u << 19)
#define TMASK (TBL - 1u)
#define PR1 2654435761u
#define PR2 805459861u

typedef float f2_t __attribute__((ext_vector_type(2)));
typedef float f4_t __attribute__((ext_vector_type(4)));

struct LevelParams {
    float scale[NLEV];
    unsigned int res[NLEV];
    unsigned int dense_mask;  // bit l set => dense (stride) indexing
};

__device__ __forceinline__ void comb_corner(
    f4_t q, f2_t ex, unsigned int je, bool godd,
    float wyz, float w0, float f0, float& acc0, float& acc1)
{
    bool hi = (je & 1u) != 0u;
    float fex = hi ? q.z : q.x, fey = hi ? q.w : q.y;  // entry je   (= corner xe)
    float fox = hi ? q.x : q.z, foy = hi ? q.y : q.w;  // entry je^1 (= corner xe+1)
    float e0x = godd ? ex.x : fex, e0y = godd ? ex.y : fey;
    float e1x = godd ? fex : fox, e1y = godd ? fey : foy;
    acc0 += wyz * (w0 * e0x + f0 * e1x);
    acc1 += wyz * (w0 * e0y + f0 * e1y);
}

// One (point, level). x-corner pairing: both x-corners usually live in one
// aligned 16B float4 (hashed: idx(x^1)=idx(x)^1; dense: idx+1).
// Hashed levels: sc0 loads (L1-bypass, L2-served) — random gathers have ~0 L1
// hit rate and the cached path burns the TCP fill port with a 128B line fill
// per 16B request.  ALL 8 loads + the waitcnt live in ONE asm statement with
// early-clobber outputs: no compiler-visible window where an RA copy could
// read an in-flight load's dest (round-6 NaN), no dest/addr aliasing
// (round-5 crash), no divergent-phi on asm outputs (loads unconditional; the
// extra e-loads for even-x lanes alias the q-load's line, so request count
// rises 6->8 but data movement is unchanged).
__device__ __forceinline__ void encode_pl(
    float c0, float c1, float c2, float s, unsigned int res, bool dense,
    const float* __restrict__ tl, float& acc0, float& acc1)
{
    // match reference op order: coords01 = (c+1)/2; pos = coords01*scale + 0.5
    float p0 = ((c0 + 1.0f) * 0.5f) * s + 0.5f;
    float p1 = ((c1 + 1.0f) * 0.5f) * s + 0.5f;
    float p2 = ((c2 + 1.0f) * 0.5f) * s + 0.5f;
    float fp0 = floorf(p0), fp1 = floorf(p1), fp2 = floorf(p2);
    float f0 = p0 - fp0, f1 = p1 - fp1, f2 = p2 - fp2;
    unsigned int g0 = (unsigned int)fp0;
    unsigned int g1 = (unsigned int)fp1;
    unsigned int g2 = (unsigned int)fp2;

    float wy0 = 1.0f - f1, wy1 = f1;
    float wz0 = 1.0f - f2, wz1 = f2;
    float w0 = 1.0f - f0;

    acc0 = 0.0f; acc1 = 0.0f;

    if (dense) {
        unsigned int res2 = res * res;
        #pragma unroll
        for (int zc = 0; zc < 2; ++zc) {
            #pragma unroll
            for (int yc = 0; yc < 2; ++yc) {
                unsigned int b = (g1 + (unsigned)yc) * res + (g2 + (unsigned)zc) * res2;
                unsigned int j0 = g0 + b;
                bool odd = (j0 & 1u) != 0u;
                f4_t q = *reinterpret_cast<const f4_t*>(tl + (size_t)(j0 & ~1u) * 2u);
                f2_t ex;
                if (odd) ex = *reinterpret_cast<const f2_t*>(tl + (size_t)(j0 + 1u) * 2u);
                float e0x = odd ? q.z : q.x, e0y = odd ? q.w : q.y;
                float e1x = odd ? ex.x : q.z, e1y = odd ? ex.y : q.w;
                float wyz = (yc ? wy1 : wy0) * (zc ? wz1 : wz0);
                acc0 += wyz * (w0 * e0x + f0 * e1x);
                acc1 += wyz * (w0 * e0y + f0 * e1y);
            }
        }
    } else {
        unsigned int hy0 = g1 * PR1, hy1 = (g1 + 1u) * PR1;
        unsigned int hz0 = g2 * PR2, hz1 = (g2 + 1u) * PR2;
        bool godd = (g0 & 1u) != 0u;
        unsigned int xe = g0 + (godd ? 1u : 0u);    // even x-corner

        unsigned int h00 = hy0 ^ hz0, h10 = hy1 ^ hz0;
        unsigned int h01 = hy0 ^ hz1, h11 = hy1 ^ hz1;
        unsigned int j00 = (xe ^ h00) & TMASK, j10 = (xe ^ h10) & TMASK;
        unsigned int j01 = (xe ^ h01) & TMASK, j11 = (xe ^ h11) & TMASK;

        const float* a00 = tl + (size_t)(j00 & ~1u) * 2u;
        const float* a10 = tl + (size_t)(j10 & ~1u) * 2u;
        const float* a01 = tl + (size_t)(j01 & ~1u) * 2u;
        const float* a11 = tl + (size_t)(j11 & ~1u) * 2u;
        const float* b00 = tl + (size_t)((g0 ^ h00) & TMASK) * 2u;
        const float* b10 = tl + (size_t)((g0 ^ h10) & TMASK) * 2u;
        const float* b01 = tl + (size_t)((g0 ^ h01) & TMASK) * 2u;
        const float* b11 = tl + (size_t)((g0 ^ h11) & TMASK) * 2u;

        f4_t q00, q10, q01, q11;
        f2_t e00, e10, e01, e11;
        asm volatile(
            "global_load_dwordx4 %0, %8, off sc0\n\t"
            "global_load_dwordx4 %1, %9, off sc0\n\t"
            "global_load_dwordx4 %2, %10, off sc0\n\t"
            "global_load_dwordx4 %3, %11, off sc0\n\t"
            "global_load_dwordx2 %4, %12, off sc0\n\t"
            "global_load_dwordx2 %5, %13, off sc0\n\t"
            "global_load_dwordx2 %6, %14, off sc0\n\t"
            "global_load_dwordx2 %7, %15, off sc0\n\t"
            "s_waitcnt vmcnt(0)"
            : "=&v"(q00), "=&v"(q10), "=&v"(q01), "=&v"(q11),
              "=&v"(e00), "=&v"(e10), "=&v"(e01), "=&v"(e11)
            : "v"(a00), "v"(a10), "v"(a01), "v"(a11),
              "v"(b00), "v"(b10), "v"(b01), "v"(b11));

        comb_corner(q00, e00, j00, godd, wy0 * wz0, w0, f0, acc0, acc1);
        comb_corner(q10, e10, j10, godd, wy1 * wz0, w0, f0, acc0, acc1);
        comb_corner(q01, e01, j01, godd, wy0 * wz1, w0, f0, acc0, acc1);
        comb_corner(q11, e11, j11, godd, wy1 * wz1, w0, f0, acc0, acc1);
    }
}

// Level-major gather: dispatch window covers ~1-2 levels -> per-XCD L2 holds
// the active level's 4 MB table. NT store: ws is write-once, keep L2 clean.
__global__ __launch_bounds__(256) void hashenc_level_kernel(
    const float* __restrict__ coords,
    const float* __restrict__ table,
    float* __restrict__ ws,           // [L][N][2]
    LevelParams lp, int npts, int blocksPerLevel)
{
    int l = blockIdx.x / blocksPerLevel;
    int n = (blockIdx.x - l * blocksPerLevel) * 256 + threadIdx.x;
    if (n >= npts) return;

    float c0 = coords[3 * n + 0];
    float c1 = coords[3 * n + 1];
    float c2 = coords[3 * n + 2];

    const float* tl = table + (size_t)l * (size_t)TBL * 2u;
    float acc0, acc1;
    encode_pl(c0, c1, c2, lp.scale[l], lp.res[l],
              (lp.dense_mask >> l) & 1u, tl, acc0, acc1);

    f2_t v; v.x = acc0; v.y = acc1;
    __builtin_nontemporal_store(v, reinterpret_cast<f2_t*>(ws) + (size_t)l * npts + n);
}

// [L][N][2] -> [N][32] via LDS tile; both global sides coalesced.
__global__ __launch_bounds__(256) void transpose_kernel(
    const float* __restrict__ ws, float* __restrict__ out, int npts)
{
    __shared__ float lds[256 * 34];
    int t = threadIdx.x;
    int p0 = blockIdx.x * 256;
    int n = p0 + t;

    if (n < npts) {
        #pragma unroll
        for (int l = 0; l < NLEV; ++l) {
            f2_t v = *(reinterpret_cast<const f2_t*>(ws) + (size_t)l * npts + n);
            *reinterpret_cast<f2_t*>(&lds[t * 34 + 2 * l]) = v;
        }
    }
    __syncthreads();

    f4_t* ob = reinterpret_cast<f4_t*>(out + (size_t)p0 * 32);
    #pragma unroll
    for (int i = 0; i < 8; ++i) {
        int fi = i * 256 + t;
        int p = fi >> 3, c = fi & 7;
        if (p0 + p < npts) {
            f2_t a = *reinterpret_cast<const f2_t*>(&lds[p * 34 + c * 4]);
            f2_t b = *reinterpret_cast<const f2_t*>(&lds[p * 34 + c * 4 + 2]);
            f4_t v; v.x = a.x; v.y = a.y; v.z = b.x; v.w = b.y;
            ob[fi] = v;
        }
    }
}

// Fallback: point-major, direct out writes (used only if ws too small).
__global__ __launch_bounds__(256) void hashenc_kernel(
    const float* __restrict__ coords,
    const float* __restrict__ table,
    float* __restrict__ out,
    LevelParams lp, int npts)
{
    int gid = blockIdx.x * 256 + threadIdx.x;
    int n = gid >> 4;
    if (n >= npts) return;
    int l = gid & 15;
    float c0 = coords[3 * n + 0];
    float c1 = coords[3 * n + 1];
    float c2 = coords[3 * n + 2];
    const float* tl = table + (size_t)l * (size_t)TBL * 2u;
    float acc0, acc1;
    encode_pl(c0, c1, c2, lp.scale[l], lp.res[l],
              (lp.dense_mask >> l) & 1u, tl, acc0, acc1);
    float2* op = reinterpret_cast<float2*>(out + (size_t)n * 32 + (size_t)l * 2);
    *op = make_float2(acc0, acc1);
}

extern "C" void kernel_launch(void* const* d_in, const int* in_sizes, int n_in,
                              void* d_out, int out_size, void* d_ws, size_t ws_size,
                              hipStream_t stream) {
    const float* coords = (const float*)d_in[0];
    const float* table  = (const float*)d_in[1];
    float* out = (float*)d_out;
    int npts = in_sizes[0] / 3;

    LevelParams lp;
    const double growth = exp((log(2048.0) - log(16.0)) / 15.0);
    unsigned int dm = 0;
    for (int l = 0; l < NLEV; ++l) {
        double sc = 16.0 * pow(growth, (double)l) - 1.0;
        lp.scale[l] = (float)sc;
        long long r = (long long)ceil(sc) + 1;
        lp.res[l] = (unsigned int)r;
        if (r * r * r <= (long long)TBL) dm |= (1u << l);
    }
    lp.dense_mask = dm;

    size_t ws_needed = (size_t)npts * NLEV * 2 * sizeof(float);
    if (ws_size >= ws_needed) {
        int blocksPerLevel = (npts + 255) / 256;
        hipLaunchKernelGGL(hashenc_level_kernel,
                           dim3(blocksPerLevel * NLEV), dim3(256), 0, stream,
                           coords, table, (float*)d_ws, lp, npts, blocksPerLevel);
        hipLaunchKernelGGL(transpose_kernel,
                           dim3(blocksPerLevel), dim3(256), 0, stream,
                           (const float*)d_ws, out, npts);
    } else {
        int total = npts * NLEV;
        int blocks = (total + 255) / 256;
        hipLaunchKernelGGL(hashenc_kernel, dim3(blocks), dim3(256), 0, stream,
                           coords, table, out, lp, npts);
    }
}

// Round 8
// 471.497 us; speedup vs baseline: 1.0985x; 1.0985x over previous
//
#include <hip/hip_runtime.h>
#include <math.h>

#define NLEV 16
#define TBL (1u << 19)
#define TMASK (TBL - 1u)
#define PR1 2654435761u
#define PR2 805459861u

typedef float f2_t __attribute__((ext_vector_type(2)));
typedef float f4_t __attribute__((ext_vector_type(4)));

struct LevelParams {
    float scale[NLEV];
    unsigned int res[NLEV];
    unsigned int dense_mask;  // bit l set => dense (stride) indexing
};

// Per-point precomputation. je = entry whose aligned 16B line we load
// (hashed: even-x corner, since idx(x^1)=idx(x)^1; dense: x=g0 corner, pair
// is je,je+1). jb = the extra 8B entry, needed iff parity condition.
struct Prep {
    unsigned int je0, je1, je2, je3;
    unsigned int jb0, jb1, jb2, jb3;
    bool godd;                        // hashed: g0 odd (uniform e-load predicate)
    float w0, f0, wyz0, wyz1, wyz2, wyz3;
};

__device__ __forceinline__ void pos_frac(float c, float s, float& fr, unsigned int& g) {
    // match reference op order: coords01 = (c+1)/2; pos = coords01*scale + 0.5
    float p = ((c + 1.0f) * 0.5f) * s + 0.5f;
    float fp = floorf(p);
    fr = p - fp;
    g = (unsigned int)fp;
}

__device__ __forceinline__ Prep prep_pt(float c0, float c1, float c2, float s,
                                        unsigned int res, bool dense) {
    Prep P;
    float f0, f1, f2v; unsigned int g0, g1, g2;
    pos_frac(c0, s, f0, g0); pos_frac(c1, s, f1, g1); pos_frac(c2, s, f2v, g2);
    P.w0 = 1.0f - f0; P.f0 = f0;
    float wy0 = 1.0f - f1, wy1 = f1, wz0 = 1.0f - f2v, wz1 = f2v;
    P.wyz0 = wy0 * wz0; P.wyz1 = wy1 * wz0; P.wyz2 = wy0 * wz1; P.wyz3 = wy1 * wz1;
    if (dense) {
        unsigned int res2 = res * res;
        unsigned int b0 = g1 * res + g2 * res2;
        unsigned int b1 = (g1 + 1u) * res + g2 * res2;
        unsigned int b2 = g1 * res + (g2 + 1u) * res2;
        unsigned int b3 = (g1 + 1u) * res + (g2 + 1u) * res2;
        P.je0 = g0 + b0; P.je1 = g0 + b1; P.je2 = g0 + b2; P.je3 = g0 + b3;
        P.jb0 = P.je0 + 1u; P.jb1 = P.je1 + 1u; P.jb2 = P.je2 + 1u; P.jb3 = P.je3 + 1u;
        P.godd = false;
    } else {
        unsigned int hy0 = g1 * PR1, hy1 = (g1 + 1u) * PR1;
        unsigned int hz0 = g2 * PR2, hz1 = (g2 + 1u) * PR2;
        bool godd = (g0 & 1u) != 0u; P.godd = godd;
        unsigned int xe = g0 + (godd ? 1u : 0u);    // even x-corner
        unsigned int h0 = hy0 ^ hz0, h1 = hy1 ^ hz0, h2 = hy0 ^ hz1, h3 = hy1 ^ hz1;
        P.je0 = (xe ^ h0) & TMASK; P.je1 = (xe ^ h1) & TMASK;
        P.je2 = (xe ^ h2) & TMASK; P.je3 = (xe ^ h3) & TMASK;
        P.jb0 = (g0 ^ h0) & TMASK; P.jb1 = (g0 ^ h1) & TMASK;
        P.jb2 = (g0 ^ h2) & TMASK; P.jb3 = (g0 ^ h3) & TMASK;
    }
    return P;
}

// 32-bit index + uniform base -> saddr-form loads (1 VGPR of address each).
__device__ __forceinline__ f4_t ldq(const float* tl, unsigned int je) {
    return *reinterpret_cast<const f4_t*>(tl + (size_t)(je & ~1u) * 2u);
}
__device__ __forceinline__ f2_t lde(const float* tl, unsigned int jb) {
    return *reinterpret_cast<const f2_t*>(tl + (size_t)jb * 2u);
}

__device__ __forceinline__ void comb_h(f4_t q, f2_t ex, unsigned int je, bool godd,
                                       float wyz, float w0, float f0, float& A0, float& A1) {
    bool hi = (je & 1u) != 0u;
    float fex = hi ? q.z : q.x, fey = hi ? q.w : q.y;  // entry je   (= corner xe)
    float fox = hi ? q.x : q.z, foy = hi ? q.y : q.w;  // entry je^1 (= corner xe+1)
    float e0x = godd ? ex.x : fex, e0y = godd ? ex.y : fey;
    float e1x = godd ? fex : fox, e1y = godd ? fey : foy;
    A0 += wyz * (w0 * e0x + f0 * e1x);
    A1 += wyz * (w0 * e0y + f0 * e1y);
}
__device__ __forceinline__ void comb_d(f4_t q, f2_t ex, unsigned int je,
                                       float wyz, float w0, float f0, float& A0, float& A1) {
    bool odd = (je & 1u) != 0u;
    float e0x = odd ? q.z : q.x, e0y = odd ? q.w : q.y;   // entry je   (corner x=g0)
    float e1x = odd ? ex.x : q.z, e1y = odd ? ex.y : q.w; // entry je+1 (corner x=g0+1)
    A0 += wyz * (w0 * e0x + f0 * e1x);
    A1 += wyz * (w0 * e0y + f0 * e1y);
}

// Level-major, 2 points per thread: doubles in-flight gather requests per
// wave (latency-bound hypothesis: 0.38 req/cyc/CU << 1/cyc TA rate at r4's
// occupancy). Plain cached loads only — sc0 regressed (r7), inline-asm
// loads crashed/NaN'd (r5/r6).
__global__ __launch_bounds__(256) void hashenc_level2_kernel(
    const float* __restrict__ coords,
    const float* __restrict__ table,
    float* __restrict__ ws,           // [L][N][2]
    LevelParams lp, int npts, int blocksPerLevel)
{
    int l = blockIdx.x / blocksPerLevel;
    int chunk = blockIdx.x - l * blocksPerLevel;
    int t = threadIdx.x;
    int n0 = chunk * 512 + t;
    int n1 = n0 + 256;
    bool v0 = n0 < npts, v1 = n1 < npts;

    // invalid lanes: clamp coords to 0 (valid in-range indices), mask store.
    float cA0 = 0.f, cA1 = 0.f, cA2 = 0.f, cB0 = 0.f, cB1 = 0.f, cB2 = 0.f;
    if (v0) { cA0 = coords[3 * n0]; cA1 = coords[3 * n0 + 1]; cA2 = coords[3 * n0 + 2]; }
    if (v1) { cB0 = coords[3 * n1]; cB1 = coords[3 * n1 + 1]; cB2 = coords[3 * n1 + 2]; }

    const float* tl = table + (size_t)l * (size_t)TBL * 2u;
    float s = lp.scale[l];
    float rA0, rA1, rB0, rB1;

    if ((lp.dense_mask >> l) & 1u) {
        unsigned int res = lp.res[l];
        Prep A = prep_pt(cA0, cA1, cA2, s, res, true);
        Prep B = prep_pt(cB0, cB1, cB2, s, res, true);
        f4_t qa0 = ldq(tl, A.je0), qa1 = ldq(tl, A.je1), qa2 = ldq(tl, A.je2), qa3 = ldq(tl, A.je3);
        f4_t qb0 = ldq(tl, B.je0), qb1 = ldq(tl, B.je1), qb2 = ldq(tl, B.je2), qb3 = ldq(tl, B.je3);
        f2_t z = {0.f, 0.f};
        f2_t ea0 = z, ea1 = z, ea2 = z, ea3 = z, eb0 = z, eb1 = z, eb2 = z, eb3 = z;
        if (A.je0 & 1u) ea0 = lde(tl, A.jb0);
        if (A.je1 & 1u) ea1 = lde(tl, A.jb1);
        if (A.je2 & 1u) ea2 = lde(tl, A.jb2);
        if (A.je3 & 1u) ea3 = lde(tl, A.jb3);
        if (B.je0 & 1u) eb0 = lde(tl, B.jb0);
        if (B.je1 & 1u) eb1 = lde(tl, B.jb1);
        if (B.je2 & 1u) eb2 = lde(tl, B.jb2);
        if (B.je3 & 1u) eb3 = lde(tl, B.jb3);
        float x0 = 0.f, x1 = 0.f, y0 = 0.f, y1 = 0.f;
        comb_d(qa0, ea0, A.je0, A.wyz0, A.w0, A.f0, x0, x1);
        comb_d(qa1, ea1, A.je1, A.wyz1, A.w0, A.f0, x0, x1);
        comb_d(qa2, ea2, A.je2, A.wyz2, A.w0, A.f0, x0, x1);
        comb_d(qa3, ea3, A.je3, A.wyz3, A.w0, A.f0, x0, x1);
        comb_d(qb0, eb0, B.je0, B.wyz0, B.w0, B.f0, y0, y1);
        comb_d(qb1, eb1, B.je1, B.wyz1, B.w0, B.f0, y0, y1);
        comb_d(qb2, eb2, B.je2, B.wyz2, B.w0, B.f0, y0, y1);
        comb_d(qb3, eb3, B.je3, B.wyz3, B.w0, B.f0, y0, y1);
        rA0 = x0; rA1 = x1; rB0 = y0; rB1 = y1;
    } else {
        Prep A = prep_pt(cA0, cA1, cA2, s, 0u, false);
        Prep B = prep_pt(cB0, cB1, cB2, s, 0u, false);
        f4_t qa0 = ldq(tl, A.je0), qa1 = ldq(tl, A.je1), qa2 = ldq(tl, A.je2), qa3 = ldq(tl, A.je3);
        f4_t qb0 = ldq(tl, B.je0), qb1 = ldq(tl, B.je1), qb2 = ldq(tl, B.je2), qb3 = ldq(tl, B.je3);
        f2_t z = {0.f, 0.f};
        f2_t ea0 = z, ea1 = z, ea2 = z, ea3 = z, eb0 = z, eb1 = z, eb2 = z, eb3 = z;
        if (A.godd) {
            ea0 = lde(tl, A.jb0); ea1 = lde(tl, A.jb1);
            ea2 = lde(tl, A.jb2); ea3 = lde(tl, A.jb3);
        }
        if (B.godd) {
            eb0 = lde(tl, B.jb0); eb1 = lde(tl, B.jb1);
            eb2 = lde(tl, B.jb2); eb3 = lde(tl, B.jb3);
        }
        float x0 = 0.f, x1 = 0.f, y0 = 0.f, y1 = 0.f;
        comb_h(qa0, ea0, A.je0, A.godd, A.wyz0, A.w0, A.f0, x0, x1);
        comb_h(qa1, ea1, A.je1, A.godd, A.wyz1, A.w0, A.f0, x0, x1);
        comb_h(qa2, ea2, A.je2, A.godd, A.wyz2, A.w0, A.f0, x0, x1);
        comb_h(qa3, ea3, A.je3, A.godd, A.wyz3, A.w0, A.f0, x0, x1);
        comb_h(qb0, eb0, B.je0, B.godd, B.wyz0, B.w0, B.f0, y0, y1);
        comb_h(qb1, eb1, B.je1, B.godd, B.wyz1, B.w0, B.f0, y0, y1);
        comb_h(qb2, eb2, B.je2, B.godd, B.wyz2, B.w0, B.f0, y0, y1);
        comb_h(qb3, eb3, B.je3, B.godd, B.wyz3, B.w0, B.f0, y0, y1);
        rA0 = x0; rA1 = x1; rB0 = y0; rB1 = y1;
    }

    // NT store: ws is write-once; keep L2 clean for the table.
    if (v0) {
        f2_t v; v.x = rA0; v.y = rA1;
        __builtin_nontemporal_store(v, reinterpret_cast<f2_t*>(ws) + (size_t)l * npts + n0);
    }
    if (v1) {
        f2_t v; v.x = rB0; v.y = rB1;
        __builtin_nontemporal_store(v, reinterpret_cast<f2_t*>(ws) + (size_t)l * npts + n1);
    }
}

// [L][N][2] -> [N][32] via LDS tile; both global sides coalesced.
__global__ __launch_bounds__(256) void transpose_kernel(
    const float* __restrict__ ws, float* __restrict__ out, int npts)
{
    __shared__ float lds[256 * 34];
    int t = threadIdx.x;
    int p0 = blockIdx.x * 256;
    int n = p0 + t;

    if (n < npts) {
        #pragma unroll
        for (int l = 0; l < NLEV; ++l) {
            f2_t v = *(reinterpret_cast<const f2_t*>(ws) + (size_t)l * npts + n);
            *reinterpret_cast<f2_t*>(&lds[t * 34 + 2 * l]) = v;
        }
    }
    __syncthreads();

    f4_t* ob = reinterpret_cast<f4_t*>(out + (size_t)p0 * 32);
    #pragma unroll
    for (int i = 0; i < 8; ++i) {
        int fi = i * 256 + t;
        int p = fi >> 3, c = fi & 7;
        if (p0 + p < npts) {
            f2_t a = *reinterpret_cast<const f2_t*>(&lds[p * 34 + c * 4]);
            f2_t b = *reinterpret_cast<const f2_t*>(&lds[p * 34 + c * 4 + 2]);
            f4_t v; v.x = a.x; v.y = a.y; v.z = b.x; v.w = b.y;
            ob[fi] = v;
        }
    }
}

// Fallback: point-major single-point, direct out writes (ws too small).
__global__ __launch_bounds__(256) void hashenc_kernel(
    const float* __restrict__ coords,
    const float* __restrict__ table,
    float* __restrict__ out,
    LevelParams lp, int npts)
{
    int gid = blockIdx.x * 256 + threadIdx.x;
    int n = gid >> 4;
    if (n >= npts) return;
    int l = gid & 15;
    float c0 = coords[3 * n + 0];
    float c1 = coords[3 * n + 1];
    float c2 = coords[3 * n + 2];
    const float* tl = table + (size_t)l * (size_t)TBL * 2u;
    bool dense = (lp.dense_mask >> l) & 1u;
    Prep A = prep_pt(c0, c1, c2, lp.scale[l], lp.res[l], dense);
    f4_t q0 = ldq(tl, A.je0), q1 = ldq(tl, A.je1), q2 = ldq(tl, A.je2), q3 = ldq(tl, A.je3);
    f2_t z = {0.f, 0.f};
    f2_t e0 = z, e1 = z, e2 = z, e3 = z;
    float x0 = 0.f, x1 = 0.f;
    if (dense) {
        if (A.je0 & 1u) e0 = lde(tl, A.jb0);
        if (A.je1 & 1u) e1 = lde(tl, A.jb1);
        if (A.je2 & 1u) e2 = lde(tl, A.jb2);
        if (A.je3 & 1u) e3 = lde(tl, A.jb3);
        comb_d(q0, e0, A.je0, A.wyz0, A.w0, A.f0, x0, x1);
        comb_d(q1, e1, A.je1, A.wyz1, A.w0, A.f0, x0, x1);
        comb_d(q2, e2, A.je2, A.wyz2, A.w0, A.f0, x0, x1);
        comb_d(q3, e3, A.je3, A.wyz3, A.w0, A.f0, x0, x1);
    } else {
        if (A.godd) { e0 = lde(tl, A.jb0); e1 = lde(tl, A.jb1); e2 = lde(tl, A.jb2); e3 = lde(tl, A.jb3); }
        comb_h(q0, e0, A.je0, A.godd, A.wyz0, A.w0, A.f0, x0, x1);
        comb_h(q1, e1, A.je1, A.godd, A.wyz1, A.w0, A.f0, x0, x1);
        comb_h(q2, e2, A.je2, A.godd, A.wyz2, A.w0, A.f0, x0, x1);
        comb_h(q3, e3, A.je3, A.godd, A.wyz3, A.w0, A.f0, x0, x1);
    }
    float2* op = reinterpret_cast<float2*>(out + (size_t)n * 32 + (size_t)l * 2);
    *op = make_float2(x0, x1);
}

extern "C" void kernel_launch(void* const* d_in, const int* in_sizes, int n_in,
                              void* d_out, int out_size, void* d_ws, size_t ws_size,
                              hipStream_t stream) {
    const float* coords = (const float*)d_in[0];
    const float* table  = (const float*)d_in[1];
    float* out = (float*)d_out;
    int npts = in_sizes[0] / 3;

    LevelParams lp;
    const double growth = exp((log(2048.0) - log(16.0)) / 15.0);
    unsigned int dm = 0;
    for (int l = 0; l < NLEV; ++l) {
        double sc = 16.0 * pow(growth, (double)l) - 1.0;
        lp.scale[l] = (float)sc;
        long long r = (long long)ceil(sc) + 1;
        lp.res[l] = (unsigned int)r;
        if (r * r * r <= (long long)TBL) dm |= (1u << l);
    }
    lp.dense_mask = dm;

    size_t ws_needed = (size_t)npts * NLEV * 2 * sizeof(float);
    if (ws_size >= ws_needed) {
        int blocksPerLevel = (npts + 511) / 512;
        hipLaunchKernelGGL(hashenc_level2_kernel,
                           dim3(blocksPerLevel * NLEV), dim3(256), 0, stream,
                           coords, table, (float*)d_ws, lp, npts, blocksPerLevel);
        int tblocks = (npts + 255) / 256;
        hipLaunchKernelGGL(transpose_kernel,
                           dim3(tblocks), dim3(256), 0, stream,
                           (const float*)d_ws, out, npts);
    } else {
        int total = npts * NLEV;
        int blocks = (total + 255) / 256;
        hipLaunchKernelGGL(hashenc_kernel, dim3(blocks), dim3(256), 0, stream,
                           coords, table, out, lp, npts);
    }
}

// Round 9
// 462.691 us; speedup vs baseline: 1.1194x; 1.0190x over previous
//
#include <hip/hip_runtime.h>
#include <math.h>

#define NLEV 16
#define TBL (1u << 19)
#define TMASK (TBL - 1u)
#define PR1 2654435761u
#define PR2 805459861u

typedef float f2_t __attribute__((ext_vector_type(2)));
typedef float f4_t __attribute__((ext_vector_type(4)));

struct LevelParams {
    float scale[NLEV];
    unsigned int res[NLEV];
    unsigned int dense_mask;  // bit l set => dense (stride) indexing
};

// One (point, level). x-corner pairing: both x-corners usually live in one
// aligned 16B float4 (hashed: idx(x^1)=idx(x)^1 since prime0==1; dense:
// idx+1). Odd-x points need one extra 8B load per (y,z) combo. Avg 6
// L2-miss lane-requests per point-level — the algorithmic floor for this
// hash (odd x+1 flips multiple bits via carry; y/z enter via primes, no
// adjacency). Measured: time tracks request count alone (r2/r4/r7/r8),
// ~2.4 cyc/request/CU == L2 random-request channel throughput.
__device__ __forceinline__ void encode_pl(
    float c0, float c1, float c2, float s, unsigned int res, bool dense,
    const float* __restrict__ tl, float& acc0, float& acc1)
{
    // match reference op order: coords01 = (c+1)/2; pos = coords01*scale + 0.5
    float p0 = ((c0 + 1.0f) * 0.5f) * s + 0.5f;
    float p1 = ((c1 + 1.0f) * 0.5f) * s + 0.5f;
    float p2 = ((c2 + 1.0f) * 0.5f) * s + 0.5f;
    float fp0 = floorf(p0), fp1 = floorf(p1), fp2 = floorf(p2);
    float f0 = p0 - fp0, f1 = p1 - fp1, f2 = p2 - fp2;
    unsigned int g0 = (unsigned int)fp0;
    unsigned int g1 = (unsigned int)fp1;
    unsigned int g2 = (unsigned int)fp2;

    float wy0 = 1.0f - f1, wy1 = f1;
    float wz0 = 1.0f - f2, wz1 = f2;
    float w0 = 1.0f - f0;

    acc0 = 0.0f; acc1 = 0.0f;

    if (dense) {
        unsigned int res2 = res * res;
        #pragma unroll
        for (int zc = 0; zc < 2; ++zc) {
            #pragma unroll
            for (int yc = 0; yc < 2; ++yc) {
                unsigned int b = (g1 + (unsigned)yc) * res + (g2 + (unsigned)zc) * res2;
                unsigned int j0 = g0 + b;
                bool odd = (j0 & 1u) != 0u;
                f4_t q = *reinterpret_cast<const f4_t*>(tl + (size_t)(j0 & ~1u) * 2u);
                f2_t ex;
                if (odd) ex = *reinterpret_cast<const f2_t*>(tl + (size_t)(j0 + 1u) * 2u);
                float e0x = odd ? q.z : q.x, e0y = odd ? q.w : q.y;
                float e1x = odd ? ex.x : q.z, e1y = odd ? ex.y : q.w;
                float wyz = (yc ? wy1 : wy0) * (zc ? wz1 : wz0);
                acc0 += wyz * (w0 * e0x + f0 * e1x);
                acc1 += wyz * (w0 * e0y + f0 * e1y);
            }
        }
    } else {
        unsigned int hy0 = g1 * PR1, hy1 = (g1 + 1u) * PR1;
        unsigned int hz0 = g2 * PR2, hz1 = (g2 + 1u) * PR2;
        bool godd = (g0 & 1u) != 0u;
        unsigned int xe = g0 + (godd ? 1u : 0u);    // even x-corner
        #pragma unroll
        for (int zc = 0; zc < 2; ++zc) {
            #pragma unroll
            for (int yc = 0; yc < 2; ++yc) {
                unsigned int hyz = (yc ? hy1 : hy0) ^ (zc ? hz1 : hz0);
                unsigned int je = (xe ^ hyz) & TMASK;
                f4_t q = *reinterpret_cast<const f4_t*>(tl + (size_t)(je & ~1u) * 2u);
                f2_t ex;
                if (godd) ex = *reinterpret_cast<const f2_t*>(tl + (size_t)((g0 ^ hyz) & TMASK) * 2u);
                bool hi = (je & 1u) != 0u;
                float fex = hi ? q.z : q.x, fey = hi ? q.w : q.y;  // entry je   (= corner xe)
                float fox = hi ? q.x : q.z, foy = hi ? q.y : q.w;  // entry je^1 (= corner xe+1)
                float e0x = godd ? ex.x : fex, e0y = godd ? ex.y : fey;
                float e1x = godd ? fex : fox, e1y = godd ? fey : foy;
                float wyz = (yc ? wy1 : wy0) * (zc ? wz1 : wz0);
                acc0 += wyz * (w0 * e0x + f0 * e1x);
                acc1 += wyz * (w0 * e0y + f0 * e1y);
            }
        }
    }
}

// Level-major gather: dispatch window covers ~1-2 levels -> per-XCD L2 holds
// the active level's 4 MB table. NT store: ws is write-once, keep L2 clean.
__global__ __launch_bounds__(256) void hashenc_level_kernel(
    const float* __restrict__ coords,
    const float* __restrict__ table,
    float* __restrict__ ws,           // [L][N][2]
    LevelParams lp, int npts, int blocksPerLevel)
{
    int l = blockIdx.x / blocksPerLevel;
    int n = (blockIdx.x - l * blocksPerLevel) * 256 + threadIdx.x;
    if (n >= npts) return;

    float c0 = coords[3 * n + 0];
    float c1 = coords[3 * n + 1];
    float c2 = coords[3 * n + 2];

    const float* tl = table + (size_t)l * (size_t)TBL * 2u;
    float acc0, acc1;
    encode_pl(c0, c1, c2, lp.scale[l], lp.res[l],
              (lp.dense_mask >> l) & 1u, tl, acc0, acc1);

    f2_t v; v.x = acc0; v.y = acc1;
    __builtin_nontemporal_store(v, reinterpret_cast<f2_t*>(ws) + (size_t)l * npts + n);
}

// [L][N][2] -> [N][32] via LDS tile. Row stride 34 floats: phase-1 writes
// 2-way bank aliases (free), phase-2 reads 4-way (1.58x, not critical).
// Both global sides fully coalesced, regular (L2-merged) stores — NT
// partial-line stores to out regressed 2.5x (r3).
__global__ __launch_bounds__(256) void transpose_kernel(
    const float* __restrict__ ws, float* __restrict__ out, int npts)
{
    __shared__ float lds[256 * 34];
    int t = threadIdx.x;
    int p0 = blockIdx.x * 256;
    int n = p0 + t;

    if (n < npts) {
        #pragma unroll
        for (int l = 0; l < NLEV; ++l) {
            f2_t v = *(reinterpret_cast<const f2_t*>(ws) + (size_t)l * npts + n);
            *reinterpret_cast<f2_t*>(&lds[t * 34 + 2 * l]) = v;
        }
    }
    __syncthreads();

    f4_t* ob = reinterpret_cast<f4_t*>(out + (size_t)p0 * 32);
    #pragma unroll
    for (int i = 0; i < 8; ++i) {
        int fi = i * 256 + t;
        int p = fi >> 3, c = fi & 7;
        if (p0 + p < npts) {
            f2_t a = *reinterpret_cast<const f2_t*>(&lds[p * 34 + c * 4]);
            f2_t b = *reinterpret_cast<const f2_t*>(&lds[p * 34 + c * 4 + 2]);
            f4_t v; v.x = a.x; v.y = a.y; v.z = b.x; v.w = b.y;
            ob[fi] = v;
        }
    }
}

// Fallback: point-major, direct out writes (used only if ws too small).
__global__ __launch_bounds__(256) void hashenc_kernel(
    const float* __restrict__ coords,
    const float* __restrict__ table,
    float* __restrict__ out,
    LevelParams lp, int npts)
{
    int gid = blockIdx.x * 256 + threadIdx.x;
    int n = gid >> 4;
    if (n >= npts) return;
    int l = gid & 15;
    float c0 = coords[3 * n + 0];
    float c1 = coords[3 * n + 1];
    float c2 = coords[3 * n + 2];
    const float* tl = table + (size_t)l * (size_t)TBL * 2u;
    float acc0, acc1;
    encode_pl(c0, c1, c2, lp.scale[l], lp.res[l],
              (lp.dense_mask >> l) & 1u, tl, acc0, acc1);
    float2* op = reinterpret_cast<float2*>(out + (size_t)n * 32 + (size_t)l * 2);
    *op = make_float2(acc0, acc1);
}

extern "C" void kernel_launch(void* const* d_in, const int* in_sizes, int n_in,
                              void* d_out, int out_size, void* d_ws, size_t ws_size,
                              hipStream_t stream) {
    const float* coords = (const float*)d_in[0];
    const float* table  = (const float*)d_in[1];
    float* out = (float*)d_out;
    int npts = in_sizes[0] / 3;

    LevelParams lp;
    const double growth = exp((log(2048.0) - log(16.0)) / 15.0);
    unsigned int dm = 0;
    for (int l = 0; l < NLEV; ++l) {
        double sc = 16.0 * pow(growth, (double)l) - 1.0;
        lp.scale[l] = (float)sc;
        long long r = (long long)ceil(sc) + 1;
        lp.res[l] = (unsigned int)r;
        if (r * r * r <= (long long)TBL) dm |= (1u << l);
    }
    lp.dense_mask = dm;

    size_t ws_needed = (size_t)npts * NLEV * 2 * sizeof(float);
    if (ws_size >= ws_needed) {
        int blocksPerLevel = (npts + 255) / 256;
        hipLaunchKernelGGL(hashenc_level_kernel,
                           dim3(blocksPerLevel * NLEV), dim3(256), 0, stream,
                           coords, table, (float*)d_ws, lp, npts, blocksPerLevel);
        hipLaunchKernelGGL(transpose_kernel,
                           dim3(blocksPerLevel), dim3(256), 0, stream,
                           (const float*)d_ws, out, npts);
    } else {
        int total = npts * NLEV;
        int blocks = (total + 255) / 256;
        hipLaunchKernelGGL(hashenc_kernel, dim3(blocks), dim3(256), 0, stream,
                           coords, table, out, lp, npts);
    }
}